// Round 6
// baseline (4412.394 us; speedup 1.0000x reference)
//
#include <hip/hip_runtime.h>
#include <math.h>

#define En 256
#define Hn 512
#define Bn 64
#define Sn 40
#define Tn 40
#define VTn 32000
#define Rn (Tn*Bn)
#define NCH 500   // 32000/64 stat chunks

typedef short v8s __attribute__((ext_vector_type(8)));
typedef float v4f __attribute__((ext_vector_type(4)));
typedef _Float16 h2v __attribute__((ext_vector_type(2)));

#if defined(__has_builtin)
#  if __has_builtin(__builtin_amdgcn_fdot2)
#    define HAVE_FDOT2 1
#  endif
#endif

__device__ __forceinline__ float dot4(float4 a, float4 b){
  return a.x*b.x + a.y*b.y + a.z*b.z + a.w*b.w;
}
__device__ __forceinline__ float sigm(float x){ return 1.f/(1.f+__expf(-x)); }
__device__ __forceinline__ unsigned short f2bf(float f){
  unsigned u = __float_as_uint(f);
  unsigned r = u + 0x7FFFu + ((u>>16)&1u);
  return (unsigned short)(r>>16);
}
__device__ __forceinline__ float bf2f(unsigned short u){
  return __uint_as_float(((unsigned)u)<<16);
}
__device__ __forceinline__ unsigned pkbf(float a, float b){
  return (unsigned)f2bf(a) | ((unsigned)f2bf(b)<<16);
}
__device__ __forceinline__ unsigned pkh(float a, float b){
  _Float16 ha = (_Float16)a, hb = (_Float16)b;
  unsigned short ua = __builtin_bit_cast(unsigned short, ha);
  unsigned short ub = __builtin_bit_cast(unsigned short, hb);
  return (unsigned)ua | ((unsigned)ub<<16);
}
__device__ __forceinline__ float fd2(unsigned w, unsigned h, float c){
#ifdef HAVE_FDOT2
  return __builtin_amdgcn_fdot2(__builtin_bit_cast(h2v,w), __builtin_bit_cast(h2v,h), c, false);
#else
  h2v a = __builtin_bit_cast(h2v,w), b = __builtin_bit_cast(h2v,h);
  return c + (float)a[0]*(float)b[0] + (float)a[1]*(float)b[1];
#endif
}

// ============ prep: zero states+sync + maps + weight converts (1 launch) ============
// ranges: 209 zero | 10 maps | 512 Whf | 512 Whb | 1024 Wd | 384 Wcomb(f16)
__global__ void prep(float* zero_base,
                     const int* __restrict__ src, const int* __restrict__ tgt,
                     const int* __restrict__ lens, int* __restrict__ grev,
                     int* __restrict__ gtgt,
                     const float* __restrict__ Whh_f, unsigned short* __restrict__ Whf16,
                     const float* __restrict__ Whh_b, unsigned short* __restrict__ Whb16,
                     const float* __restrict__ Whh_d, const float* __restrict__ Wih_d,
                     unsigned short* __restrict__ Wd16,
                     const float* __restrict__ Wcomb, unsigned short* __restrict__ Wc16){
  int blk = blockIdx.x, tid = threadIdx.x;
  if (blk < 209){
    ((float4*)zero_base)[blk*256 + tid] = make_float4(0.f,0.f,0.f,0.f);
    return;
  }
  blk -= 209;
  if (blk < 10){
    int r = blk*256 + tid;
    if (r < Bn*Sn){
      int b = r/Sn, s = r%Sn;
      int j = lens[b]-1-s;
      grev[r] = (j>=0) ? src[b*Sn+j] : -1;
      int t2 = r>>6, b2 = r&63;
      gtgt[r] = tgt[b2*Tn + t2];
    }
    return;
  }
  blk -= 10;
  if (blk < 512){
    size_t e = ((size_t)blk*256 + tid)*8;
    float4 a = *(const float4*)(Whh_f+e), b = *(const float4*)(Whh_f+e+4);
    uint4 u; u.x=pkbf(a.x,a.y); u.y=pkbf(a.z,a.w); u.z=pkbf(b.x,b.y); u.w=pkbf(b.z,b.w);
    *(uint4*)(Whf16+e) = u;
    return;
  }
  blk -= 512;
  if (blk < 512){
    size_t e = ((size_t)blk*256 + tid)*8;
    float4 a = *(const float4*)(Whh_b+e), b = *(const float4*)(Whh_b+e+4);
    uint4 u; u.x=pkbf(a.x,a.y); u.y=pkbf(a.z,a.w); u.z=pkbf(b.x,b.y); u.w=pkbf(b.z,b.w);
    *(uint4*)(Whb16+e) = u;
    return;
  }
  blk -= 512;
  if (blk < 1024){
    size_t e = ((size_t)blk*256 + tid)*8;     // [2048][1024]: k<512 Whh_d, else Wih_d cols 256+
    int row = (int)(e>>10), k = (int)(e&1023);
    const float* sp = (k<512) ? (Whh_d + (size_t)row*512 + k)
                              : (Wih_d + (size_t)row*768 + 256 + (k-512));
    float4 a = *(const float4*)sp, b = *(const float4*)(sp+4);
    uint4 u; u.x=pkbf(a.x,a.y); u.y=pkbf(a.z,a.w); u.z=pkbf(b.x,b.y); u.w=pkbf(b.z,b.w);
    *(uint4*)(Wd16+e) = u;
    return;
  }
  blk -= 1024;
  { // Wcomb -> f16, 384 blocks
    size_t e = ((size_t)blk*256 + tid)*8;
    float4 a = *(const float4*)(Wcomb+e), b = *(const float4*)(Wcomb+e+4);
    uint4 u; u.x=pkh(a.x,a.y); u.y=pkh(a.z,a.w); u.z=pkh(b.x,b.y); u.w=pkh(b.z,b.w);
    *(uint4*)(Wc16+e) = u;
  }
}

// ============ generic bf16-staging MFMA GEMM: C[M,N] = gather(A)f32 @ Bf32^T + bias ============
struct GArg {
  const float* A; const int* gth; int lda;
  const float* B; int ldb;
  const float* bias; float* C; int ldc; int K;
};
struct GArg3 { GArg a[3]; };

__global__ __launch_bounds__(256) void ggemm(GArg3 p3){
  GArg d = p3.a[blockIdx.z];
  __shared__ unsigned short Abf[128*64];
  __shared__ unsigned short Bbf[128*64];
  const int n0 = blockIdx.x*128, r0 = blockIdx.y*128;
  const int tid = threadIdx.x;
  const int w = tid>>6, lane = tid&63;
  const int wr = w>>1, wc = w&1;
  v4f acc[4][4];
#pragma unroll
  for (int i=0;i<4;++i)
#pragma unroll
    for (int j=0;j<4;++j) acc[i][j] = (v4f){0.f,0.f,0.f,0.f};
  const int srow = tid>>1, kc = (tid&1)*32;
  int ar = d.gth ? d.gth[r0+srow] : (r0+srow);
  const float* Arow = (ar>=0) ? (d.A + (size_t)ar*d.lda) : nullptr;
  const float* Brow = d.B + (size_t)(n0+srow)*d.ldb;
  for (int kb=0; kb<d.K; kb+=64){
    __syncthreads();
#pragma unroll
    for (int c=0;c<4;++c){
      int k = kc + c*8;
      int swz = k ^ ((srow&7)<<3);
      uint4 ua;
      if (Arow){
        float4 x0 = *(const float4*)(Arow+kb+k);
        float4 x1 = *(const float4*)(Arow+kb+k+4);
        ua.x=pkbf(x0.x,x0.y); ua.y=pkbf(x0.z,x0.w); ua.z=pkbf(x1.x,x1.y); ua.w=pkbf(x1.z,x1.w);
      } else ua = make_uint4(0,0,0,0);
      *(uint4*)&Abf[srow*64 + swz] = ua;
      float4 y0 = *(const float4*)(Brow+kb+k);
      float4 y1 = *(const float4*)(Brow+kb+k+4);
      uint4 ub; ub.x=pkbf(y0.x,y0.y); ub.y=pkbf(y0.z,y0.w); ub.z=pkbf(y1.x,y1.y); ub.w=pkbf(y1.z,y1.w);
      *(uint4*)&Bbf[srow*64 + swz] = ub;
    }
    __syncthreads();
#pragma unroll
    for (int kk=0; kk<64; kk+=32){
      int kfr = kk + (lane>>4)*8;
      v8s bfr[4];
#pragma unroll
      for (int ni=0;ni<4;++ni){
        int brow = wc*64 + ni*16 + (lane&15);
        bfr[ni] = *(const v8s*)&Bbf[brow*64 + (kfr ^ ((brow&7)<<3))];
      }
#pragma unroll
      for (int mi=0;mi<4;++mi){
        int arl = wr*64 + mi*16 + (lane&15);
        v8s af = *(const v8s*)&Abf[arl*64 + (kfr ^ ((arl&7)<<3))];
#pragma unroll
        for (int ni=0;ni<4;++ni)
          acc[mi][ni] = __builtin_amdgcn_mfma_f32_16x16x32_bf16(af, bfr[ni], acc[mi][ni], 0,0,0);
      }
    }
  }
#pragma unroll
  for (int ni=0;ni<4;++ni){
    int col = n0 + wc*64 + ni*16 + (lane&15);
    float bb = d.bias[col];
#pragma unroll
    for (int mi=0;mi<4;++mi)
#pragma unroll
      for (int r=0;r<4;++r){
        int row = r0 + wr*64 + mi*16 + (lane>>4)*4 + r;
        d.C[(size_t)row*d.ldc + col] = acc[mi][ni][r] + bb;
      }
  }
}

// ============ persistent encoder: 64 blocks, 40 steps, atomic barrier between steps ============
__global__ __launch_bounds__(256) void enc_scan(
    unsigned short* __restrict__ hf0, unsigned short* __restrict__ hf1,
    unsigned short* __restrict__ hb0, unsigned short* __restrict__ hb1,
    float* __restrict__ cF, float* __restrict__ cB,
    const unsigned short* __restrict__ Wf16, const unsigned short* __restrict__ Wb16,
    const float* __restrict__ Gf, const float* __restrict__ Gb,
    float* __restrict__ encH, float* __restrict__ outR,
    const int* __restrict__ lens, int* __restrict__ bar){
  __shared__ unsigned short Wls[64*64];
  __shared__ unsigned short Hls[64*64];
  __shared__ float Cls[64][66];
  const int bx = blockIdx.x;
  const int dir = bx>>5;
  const int u0 = (bx&31)*16;
  const unsigned short* W16 = dir ? Wb16 : Wf16;
  float* c = dir ? cB : cF;
  const float* G = dir ? Gb : Gf;
  const int tid = threadIdx.x, w = tid>>6, lane = tid&63;
  const int l = tid>>2;
  const int kc4 = (tid&3)*16;
  const int grow = (l>>4)*512 + u0 + (l&15);
  const unsigned short* Wrow = W16 + (size_t)grow*512;
#pragma unroll 1
  for (int s=0; s<Sn; ++s){
    const unsigned short* hin = dir ? ((s&1)?hb1:hb0) : ((s&1)?hf1:hf0);
    unsigned short* hout      = dir ? ((s&1)?hb0:hb1) : ((s&1)?hf0:hf1);
    const unsigned short* Hrow = hin + (size_t)l*512;
    v4f acc[4];
#pragma unroll
    for (int ni=0;ni<4;++ni) acc[ni] = (v4f){0.f,0.f,0.f,0.f};
    for (int kb=0; kb<512; kb+=64){
      __syncthreads();
#pragma unroll
      for (int c2=0;c2<2;++c2){
        int k = kc4 + c2*8;
        int swz = k ^ ((l&7)<<3);
        *(uint4*)&Wls[l*64+swz] = *(const uint4*)(Wrow + kb + k);
        *(uint4*)&Hls[l*64+swz] = *(const uint4*)(Hrow + kb + k);
      }
      __syncthreads();
#pragma unroll
      for (int kk=0; kk<64; kk+=32){
        int kfr = kk + (lane>>4)*8;
        int mrow = w*16 + (lane&15);
        v8s af = *(const v8s*)&Wls[mrow*64 + (kfr ^ ((mrow&7)<<3))];
#pragma unroll
        for (int ni=0;ni<4;++ni){
          int brow = ni*16 + (lane&15);
          v8s bf = *(const v8s*)&Hls[brow*64 + (kfr ^ ((brow&7)<<3))];
          acc[ni] = __builtin_amdgcn_mfma_f32_16x16x32_bf16(af, bf, acc[ni], 0,0,0);
        }
      }
    }
#pragma unroll
    for (int ni=0;ni<4;++ni)
#pragma unroll
      for (int r=0;r<4;++r)
        Cls[w*16 + (lane>>4)*4 + r][ni*16 + (lane&15)] = acc[ni][r];
    __syncthreads();
    const int u_l = tid&15, bq = tid>>4;
#pragma unroll
    for (int j=0;j<4;++j){
      int b = bq + j*16;
      size_t gidx = ((size_t)(b*Sn+s))*2048 + u0 + u_l;
      float gi = Cls[u_l][b]      + G[gidx];
      float gf = Cls[16+u_l][b]   + G[gidx+512];
      float gg = Cls[32+u_l][b]   + G[gidx+1024];
      float go = Cls[48+u_l][b]   + G[gidx+1536];
      int bu = b*512 + u0 + u_l;
      bool valid = s < lens[b];
      float cp = c[bu];
      float cn = sigm(gf)*cp + sigm(gi)*tanhf(gg);
      float hn = sigm(go)*tanhf(cn);
      c[bu] = valid ? cn : cp;
      hout[bu] = valid ? f2bf(hn) : hin[bu];
      if (dir==0) encH[((size_t)(b*Sn+s))*1024 + u0+u_l] = valid ? hn : 0.f;
      else        outR[((size_t)(b*Sn+s))*512  + u0+u_l] = valid ? hn : 0.f;
    }
    if (s < Sn-1){
      __syncthreads();
      if (tid==0){
        __threadfence();
        __hip_atomic_fetch_add(bar, 1, __ATOMIC_RELEASE, __HIP_MEMORY_SCOPE_AGENT);
        const int target = 64*(s+1);
        long it = 0;
        while (__hip_atomic_load(bar, __ATOMIC_ACQUIRE, __HIP_MEMORY_SCOPE_AGENT) < target
               && it < 2000000000L) ++it;
      }
      __syncthreads();
      __threadfence();
    }
  }
}

// ============ mid: proj-h/proj-c + reverse-bwd + Wvoc cvt (1 launch) ============
// ranges: 128 proj | 640 reverse | 8000 Wvoc
__global__ void mid_fused(const unsigned short* __restrict__ h16f,
                          const unsigned short* __restrict__ h16b,
                          const float* __restrict__ cF, const float* __restrict__ cB,
                          const float* __restrict__ Whp, const float* __restrict__ bhp,
                          const float* __restrict__ Wcp, const float* __restrict__ bcp,
                          unsigned short* __restrict__ H0, float* __restrict__ dC,
                          const float* __restrict__ outR, const int* __restrict__ lens,
                          float* __restrict__ encH,
                          const float* __restrict__ Wvoc, unsigned short* __restrict__ W16){
  int blk = blockIdx.x, tid = threadIdx.x;
  if (blk < 128){
    int isC = blk >= 64;
    int idx = (blk & 63)*256 + tid;
#pragma unroll
    for (int e=0;e<2;++e){
      int o = idx*2 + e;
      int b = o>>9, u = o&511;
      if (!isC){
        const float* wr = Whp + (size_t)u*1024;
        float acc = bhp[u];
        const uint4* hf4 = (const uint4*)(h16f + (size_t)b*512);
        for (int q=0;q<64;++q){
          uint4 v = hf4[q];
          unsigned uu[4] = {v.x,v.y,v.z,v.w};
#pragma unroll
          for (int i2=0;i2<4;++i2){
            acc += bf2f((unsigned short)(uu[i2]&0xFFFF))*wr[q*8+i2*2];
            acc += bf2f((unsigned short)(uu[i2]>>16))   *wr[q*8+i2*2+1];
          }
        }
        const uint4* hb4 = (const uint4*)(h16b + (size_t)b*512);
        const float* wr2 = wr + 512;
        for (int q=0;q<64;++q){
          uint4 v = hb4[q];
          unsigned uu[4] = {v.x,v.y,v.z,v.w};
#pragma unroll
          for (int i2=0;i2<4;++i2){
            acc += bf2f((unsigned short)(uu[i2]&0xFFFF))*wr2[q*8+i2*2];
            acc += bf2f((unsigned short)(uu[i2]>>16))   *wr2[q*8+i2*2+1];
          }
        }
        H0[b*512 + u] = f2bf(acc);
      } else {
        const float4* w4 = (const float4*)(Wcp + (size_t)u*1024);
        float acc = bcp[u];
        const float4* x1 = (const float4*)(cF + (size_t)b*512);
        const float4* x2 = (const float4*)(cB + (size_t)b*512);
        for (int q=0;q<128;++q) acc += dot4(x1[q], w4[q]);
        for (int q=0;q<128;++q) acc += dot4(x2[q], w4[128+q]);
        dC[b*512 + u] = acc;
      }
    }
    return;
  }
  blk -= 128;
  if (blk < 640){
    int e = (blk*256 + tid)*8;       // < 1,310,720
    int u = e & 511;
    int bsi = e >> 9;
    int s = bsi % Sn, b = bsi / Sn;
    int len = lens[b];
    float4 v0 = make_float4(0,0,0,0), v1 = make_float4(0,0,0,0);
    if (s < len){
      int j = len-1-s;
      const float* sp = outR + ((size_t)(b*Sn+j))*512 + u;
      v0 = *(const float4*)sp; v1 = *(const float4*)(sp+4);
    }
    float* dp = encH + ((size_t)(b*Sn+s))*1024 + 512 + u;
    *(float4*)dp = v0; *(float4*)(dp+4) = v1;
    return;
  }
  blk -= 640;
  { // Wvoc cvt, 8000 blocks
    size_t e = ((size_t)blk*256 + tid)*8;
    float4 a = *(const float4*)(Wvoc+e), b = *(const float4*)(Wvoc+e+4);
    uint4 u; u.x=pkbf(a.x,a.y); u.y=pkbf(a.z,a.w); u.z=pkbf(b.x,b.y); u.w=pkbf(b.z,b.w);
    *(uint4*)(W16+e) = u;
  }
}

// ============ decoder step: 96 blocks, producer/consumer flags ============
// blocks 0..63 (b): attention+combine for step t-1 -> obuf + A16 row t-1, then flag.
// blocks 64..95 (u): gates MFMA h-part (K=512), wait flag, o-part (K=512), LSTM -> Hnext.
__global__ __launch_bounds__(256) void dec_step(
    const unsigned short* __restrict__ Wd16,
    const unsigned short* __restrict__ Hcur, unsigned short* __restrict__ Hnext,
    unsigned short* __restrict__ obuf,
    const float* __restrict__ Gdy, float* __restrict__ dC,
    const float* __restrict__ eprj, const float* __restrict__ encH,
    const int* __restrict__ lens,
    const unsigned short* __restrict__ Wc16, const float* __restrict__ bcomb,
    unsigned short* __restrict__ A16, int* __restrict__ cnt, int t){
  const int blk = blockIdx.x, tid = threadIdx.x;
  if (blk < Bn){
    if (t == 0) return;
    const int b = blk;
    __shared__ __align__(16) float hs[512];
    __shared__ __align__(16) float als[1024];
    __shared__ float es[Sn], sal[Sn];
    __shared__ float sinv;
    __shared__ __align__(16) unsigned ha16[768];
    for (int i=tid; i<512; i+=256) hs[i] = bf2f(Hcur[b*512 + i]);
    __syncthreads();
    const int wv = tid>>6, lane = tid&63;
    const int len = lens[b];
    for (int si=0; si<10; ++si){
      int s2 = wv*10 + si;
      const float* pr = eprj + ((size_t)(b*Sn+s2))*512 + lane*8;
      float4 p0 = *(const float4*)pr, p1 = *(const float4*)(pr+4);
      const float* hh = hs + lane*8;
      float4 h0 = *(const float4*)hh, h1 = *(const float4*)(hh+4);
      float a = dot4(p0,h0) + dot4(p1,h1);
#pragma unroll
      for (int off=32; off; off>>=1) a += __shfl_down(a, off);
      if (lane==0) es[s2] = (s2>=1 && s2<len) ? -INFINITY : a;
    }
    __syncthreads();
    if (tid < 64){
      float e2 = (tid<Sn) ? es[tid] : -INFINITY;
      float m = e2;
#pragma unroll
      for (int off=32; off; off>>=1) m = fmaxf(m, __shfl_xor(m, off));
      float p = (tid<Sn) ? __expf(e2-m) : 0.f;
      float sum = p;
#pragma unroll
      for (int off=32; off; off>>=1) sum += __shfl_xor(sum, off);
      if (tid<Sn) sal[tid] = p;
      if (tid==0) sinv = 1.f/sum;
    }
    __syncthreads();
    float inv = sinv;
#pragma unroll
    for (int dq=0; dq<4; ++dq){
      int d = dq*256 + tid;
      float acc = 0.f;
      for (int s2=0; s2<Sn; ++s2) acc += sal[s2]*encH[((size_t)(b*Sn+s2))*1024 + d];
      als[d] = acc*inv;
    }
    __syncthreads();
    for (int p=tid; p<768; p+=256){
      int i0 = 2*p, i1 = 2*p+1;
      float x0 = (i0<512) ? hs[i0] : als[i0-512];
      float x1 = (i1<512) ? hs[i1] : als[i1-512];
      ha16[p] = pkh(x0, x1);
    }
    __syncthreads();
    const uint4* hp = (const uint4*)ha16;
#pragma unroll
    for (int rr=0; rr<2; ++rr){
      int row = tid + rr*256;
      const uint4* wp = (const uint4*)(Wc16 + (size_t)row*1536);
      float a0 = 0.f;
#pragma unroll 4
      for (int qq=0; qq<192; ++qq){
        uint4 w4 = wp[qq];
        uint4 h4 = hp[qq];
        a0 = fd2(w4.x, h4.x, a0);
        a0 = fd2(w4.y, h4.y, a0);
        a0 = fd2(w4.z, h4.z, a0);
        a0 = fd2(w4.w, h4.w, a0);
      }
      float O = tanhf(a0 + bcomb[row]);
      unsigned short ob = f2bf(O);
      obuf[b*512 + row] = ob;
      A16[((size_t)((t-1)*Bn + b))*512 + row] = ob;
    }
    __threadfence();
    __syncthreads();
    if (tid==0)
      __hip_atomic_fetch_add(&cnt[t], 1, __ATOMIC_RELEASE, __HIP_MEMORY_SCOPE_AGENT);
    return;
  }
  // ---- consumer: gates MFMA + LSTM ----
  if (t == Tn) return;
  __shared__ unsigned short Wls[64*64];
  __shared__ unsigned short Hls[64*64];
  __shared__ float Cls[64][66];
  const int u0 = (blk - Bn)*16;
  const int w = tid>>6, lane = tid&63;
  v4f acc[4];
#pragma unroll
  for (int ni=0;ni<4;++ni) acc[ni] = (v4f){0.f,0.f,0.f,0.f};
  const int l = tid>>2;
  const int kc4 = (tid&3)*16;
  const int grow = (l>>4)*512 + u0 + (l&15);
  const unsigned short* Wrow = Wd16 + (size_t)grow*1024;
  const int kmax = t ? 1024 : 512;
  for (int kb=0; kb<kmax; kb+=64){
    if (kb == 512){
      __syncthreads();
      if (tid==0){
        long it = 0;
        while (__hip_atomic_load(&cnt[t], __ATOMIC_ACQUIRE, __HIP_MEMORY_SCOPE_AGENT) < Bn
               && it < 2000000000L) ++it;
      }
      __syncthreads();
      __threadfence();
    }
    const unsigned short* src = (kb < 512) ? (Hcur + (size_t)l*512 + kb)
                                           : (obuf + (size_t)l*512 + (kb-512));
    __syncthreads();
#pragma unroll
    for (int c2=0;c2<2;++c2){
      int k = kc4 + c2*8;
      int swz = k ^ ((l&7)<<3);
      *(uint4*)&Wls[l*64+swz] = *(const uint4*)(Wrow + kb + k);
      *(uint4*)&Hls[l*64+swz] = *(const uint4*)(src + k);
    }
    __syncthreads();
#pragma unroll
    for (int kk=0; kk<64; kk+=32){
      int kfr = kk + (lane>>4)*8;
      int mrow = w*16 + (lane&15);
      v8s af = *(const v8s*)&Wls[mrow*64 + (kfr ^ ((mrow&7)<<3))];
#pragma unroll
      for (int ni=0;ni<4;++ni){
        int brow = ni*16 + (lane&15);
        v8s bf = *(const v8s*)&Hls[brow*64 + (kfr ^ ((brow&7)<<3))];
        acc[ni] = __builtin_amdgcn_mfma_f32_16x16x32_bf16(af, bf, acc[ni], 0,0,0);
      }
    }
  }
#pragma unroll
  for (int ni=0;ni<4;++ni)
#pragma unroll
    for (int r=0;r<4;++r)
      Cls[w*16 + (lane>>4)*4 + r][ni*16 + (lane&15)] = acc[ni][r];
  __syncthreads();
  const int u_l = tid&15, bq = tid>>4;
#pragma unroll
  for (int j=0;j<4;++j){
    int b = bq + j*16;
    size_t gidx = ((size_t)(t*Bn+b))*2048 + u0 + u_l;
    float gi = Cls[u_l][b]      + Gdy[gidx];
    float gf = Cls[16+u_l][b]   + Gdy[gidx+512];
    float gg = Cls[32+u_l][b]   + Gdy[gidx+1024];
    float go = Cls[48+u_l][b]   + Gdy[gidx+1536];
    int bu = b*512 + u0 + u_l;
    float cp = dC[bu];
    float cn = sigm(gf)*cp + sigm(gi)*tanhf(gg);
    float hn = sigm(go)*tanhf(cn);
    dC[bu] = cn;
    Hnext[b*512 + u0 + u_l] = f2bf(hn);
  }
}

// ============ vocab MFMA (round-4 proven): 128x128 tiles, fused per-64-col stats ============
__global__ __launch_bounds__(256) void vocab_mfma(
    const unsigned short* __restrict__ A16, const unsigned short* __restrict__ W16,
    const float* __restrict__ bv, float* __restrict__ stats){
  __shared__ unsigned short Abf[128*64];
  __shared__ unsigned short Bbf[128*64];
  const int vb = blockIdx.x, rb = blockIdx.y;
  const int r0 = rb*128, v0 = vb*128;
  const int tid = threadIdx.x;
  const int w = tid>>6, lane = tid&63;
  const int wr = w>>1, wc = w&1;
  v4f acc[4][4];
#pragma unroll
  for (int i=0;i<4;++i)
#pragma unroll
    for (int j=0;j<4;++j) acc[i][j] = (v4f){0.f,0.f,0.f,0.f};
  const int srow = tid>>1;
  const int sk0  = (tid&1)*8;
  const int arow = wr*64 + (lane&15);
  const int brow = wc*64 + (lane&15);
  const int kfrag = (lane>>4)*8;
  for (int ks=0; ks<8; ++ks){
    const int kb = ks*64;
    __syncthreads();
#pragma unroll
    for (int c=0;c<4;++c){
      int k = sk0 + c*16;
      int swz = k ^ ((srow&7)<<3);
      *(uint4*)&Abf[srow*64 + swz] = *(const uint4*)(A16 + (size_t)(r0+srow)*512 + kb + k);
      *(uint4*)&Bbf[srow*64 + swz] = *(const uint4*)(W16 + (size_t)(v0+srow)*512 + kb + k);
    }
    __syncthreads();
#pragma unroll
    for (int kk=0; kk<64; kk+=32){
      v8s af[4], bf[4];
#pragma unroll
      for (int mi=0;mi<4;++mi){
        int row = arow + mi*16;
        int k = kk + kfrag;
        af[mi] = *(const v8s*)&Abf[row*64 + (k ^ ((row&7)<<3))];
      }
#pragma unroll
      for (int ni=0;ni<4;++ni){
        int row = brow + ni*16;
        int k = kk + kfrag;
        bf[ni] = *(const v8s*)&Bbf[row*64 + (k ^ ((row&7)<<3))];
      }
#pragma unroll
      for (int mi=0;mi<4;++mi)
#pragma unroll
        for (int ni=0;ni<4;++ni)
          acc[mi][ni] = __builtin_amdgcn_mfma_f32_16x16x32_bf16(af[mi], bf[ni], acc[mi][ni], 0,0,0);
    }
  }
  float bj[4];
#pragma unroll
  for (int ni=0;ni<4;++ni) bj[ni] = bv[v0 + wc*64 + ni*16 + (lane&15)];
#pragma unroll
  for (int mi=0;mi<4;++mi){
#pragma unroll
    for (int r=0;r<4;++r){
      float x0 = acc[mi][0][r]+bj[0], x1 = acc[mi][1][r]+bj[1];
      float x2 = acc[mi][2][r]+bj[2], x3 = acc[mi][3][r]+bj[3];
      float mx = fmaxf(fmaxf(x0,x1), fmaxf(x2,x3));
#pragma unroll
      for (int off=1; off<16; off<<=1) mx = fmaxf(mx, __shfl_xor(mx, off));
      float se = __expf(x0-mx)+__expf(x1-mx)+__expf(x2-mx)+__expf(x3-mx);
#pragma unroll
      for (int off=1; off<16; off<<=1) se += __shfl_xor(se, off);
      if ((lane&15)==0){
        int row = r0 + wr*64 + mi*16 + (lane>>4)*4 + r;
        int chunk = vb*2 + wc;
        size_t o = ((size_t)row*NCH + chunk)*2;
        stats[o]   = mx;
        stats[o+1] = se;
      }
    }
  }
}

// ============ tail: lse + target logit + atomic mean (1 launch) ============
__global__ void tail(const float* __restrict__ stats, const unsigned short* __restrict__ A16,
                     const float* __restrict__ Wvoc, const float* __restrict__ bvoc,
                     const int* __restrict__ gtgt, float* __restrict__ out){
  int r = blockIdx.x*4 + (threadIdx.x>>6);
  int lane = threadIdx.x & 63;
  const float* st = stats + (size_t)r*NCH*2;
  float M = -INFINITY;
  for (int c=lane; c<NCH; c+=64) M = fmaxf(M, st[2*c]);
#pragma unroll
  for (int off=32; off; off>>=1) M = fmaxf(M, __shfl_xor(M, off));
  float S = 0.f;
  for (int c=lane; c<NCH; c+=64) S += __expf(st[2*c]-M)*st[2*c+1];
#pragma unroll
  for (int off=32; off; off>>=1) S += __shfl_xor(S, off);
  int v = gtgt[r];
  int k = lane*8;
  uint4 a4 = *(const uint4*)(A16 + (size_t)r*512 + k);
  const float* wvp = Wvoc + (size_t)v*512 + k;
  float4 w0 = *(const float4*)wvp, w1 = *(const float4*)(wvp+4);
  unsigned uu[4] = {a4.x, a4.y, a4.z, a4.w};
  float dot = 0.f;
  dot += bf2f((unsigned short)(uu[0]&0xFFFF))*w0.x + bf2f((unsigned short)(uu[0]>>16))*w0.y;
  dot += bf2f((unsigned short)(uu[1]&0xFFFF))*w0.z + bf2f((unsigned short)(uu[1]>>16))*w0.w;
  dot += bf2f((unsigned short)(uu[2]&0xFFFF))*w1.x + bf2f((unsigned short)(uu[2]>>16))*w1.y;
  dot += bf2f((unsigned short)(uu[3]&0xFFFF))*w1.z + bf2f((unsigned short)(uu[3]>>16))*w1.w;
#pragma unroll
  for (int off=32; off; off>>=1) dot += __shfl_down(dot, off);
  if (lane==0){
    float lse = M + logf(S);
    float nll = lse - (dot + bvoc[v]);
    atomicAdd(out, nll * (1.0f/(float)Rn));
  }
}

extern "C" void kernel_launch(void* const* d_in, const int* in_sizes, int n_in,
                              void* d_out, int out_size, void* d_ws, size_t ws_size,
                              hipStream_t stream){
  (void)in_sizes; (void)n_in; (void)out_size; (void)ws_size;
  const int*   srcP  = (const int*)  d_in[0];
  const int*   tgtP  = (const int*)  d_in[1];
  const int*   lens  = (const int*)  d_in[2];
  const float* semb  = (const float*)d_in[3];
  const float* temb  = (const float*)d_in[4];
  const float* Wih_f = (const float*)d_in[5];
  const float* Whh_f = (const float*)d_in[6];
  const float* b_f   = (const float*)d_in[7];
  const float* Wih_b = (const float*)d_in[8];
  const float* Whh_b = (const float*)d_in[9];
  const float* b_b   = (const float*)d_in[10];
  const float* Wih_d = (const float*)d_in[11];
  const float* Whh_d = (const float*)d_in[12];
  const float* b_d   = (const float*)d_in[13];
  const float* Whp   = (const float*)d_in[14];
  const float* bhp   = (const float*)d_in[15];
  const float* Wcp   = (const float*)d_in[16];
  const float* bcp   = (const float*)d_in[17];
  const float* Watt  = (const float*)d_in[18];
  const float* batt  = (const float*)d_in[19];
  const float* Wcomb = (const float*)d_in[20];
  const float* bcomb = (const float*)d_in[21];
  const float* Wvoc  = (const float*)d_in[22];
  const float* bvoc  = (const float*)d_in[23];

  float* w = (float*)d_ws;
  size_t off = 0;
  auto alloc = [&](size_t n){ float* p = w + off; off += n; return p; };
  float* encH = alloc(2621440);          // [2560][1024]; stats alias after decoder
  float* outR = alloc(1310720);
  float* eprj = alloc(1310720);
  float* Gf   = alloc(5242880);          // Gf+Gb aliased by W16 after encoder
  float* Gb   = alloc(5242880);
  float* Gdy  = alloc(5242880);
  unsigned short* A16   = (unsigned short*)alloc(655360);
  unsigned short* Whf16 = (unsigned short*)alloc(524288);
  unsigned short* Whb16 = (unsigned short*)alloc(524288);
  unsigned short* Wd16  = (unsigned short*)alloc(1048576);
  unsigned short* Wc16  = (unsigned short*)alloc(393216);
  float* zero_base = w + off;            // 209*1024 = 214016 words, zeroed by prep
  float* cF = alloc(32768);
  float* cB = alloc(32768);
  float* dC = alloc(32768);
  unsigned short* h16f0 = (unsigned short*)alloc(16384);
  unsigned short* h16f1 = (unsigned short*)alloc(16384);
  unsigned short* h16b0 = (unsigned short*)alloc(16384);
  unsigned short* h16b1 = (unsigned short*)alloc(16384);
  unsigned short* H0    = (unsigned short*)alloc(16384);
  unsigned short* H1    = (unsigned short*)alloc(16384);
  unsigned short* obuf  = (unsigned short*)alloc(16384);
  int* syncv = (int*)alloc(1024);        // [0]=enc barrier, [1..40]=dec flags
  int* grev = (int*)alloc(2560);
  int* gtgt = (int*)alloc(2560);
  unsigned short* W16 = (unsigned short*)Gf;   // over Gf+Gb (dead post-encoder)
  float* stats = encH;                          // over encH (dead post-decoder)

  hipMemsetAsync(d_out, 0, sizeof(float), stream);
  prep<<<2651, 256, 0, stream>>>(zero_base, srcP, tgtP, lens, grev, gtgt,
                                 Whh_f, Whf16, Whh_b, Whb16, Whh_d, Wih_d, Wd16,
                                 Wcomb, Wc16);
  {
    GArg3 g;
    g.a[0] = GArg{semb, srcP, En, Wih_f, En,  b_f, Gf,  2048, En};
    g.a[1] = GArg{semb, grev, En, Wih_b, En,  b_b, Gb,  2048, En};
    g.a[2] = GArg{temb, gtgt, En, Wih_d, 768, b_d, Gdy, 2048, En};
    ggemm<<<dim3(16,20,3), 256, 0, stream>>>(g);
  }
  enc_scan<<<64, 256, 0, stream>>>(h16f0, h16f1, h16b0, h16b1, cF, cB,
                                   Whf16, Whb16, Gf, Gb, encH, outR, lens, syncv);
  mid_fused<<<8768, 256, 0, stream>>>(h16f0, h16b0, cF, cB, Whp, bhp, Wcp, bcp,
                                      H0, dC, outR, lens, encH, Wvoc, W16);
  {
    GArg3 g;
    g.a[0] = GArg{encH, nullptr, 1024, Watt, 1024, batt, eprj, 512, 1024};
    g.a[1] = g.a[0]; g.a[2] = g.a[0];
    ggemm<<<dim3(4,20,1), 256, 0, stream>>>(g);
  }
  unsigned short* Hb[2] = {H0, H1};
  for (int t=0; t<=Tn; ++t)
    dec_step<<<96, 256, 0, stream>>>(Wd16, Hb[t&1], Hb[(t+1)&1], obuf, Gdy, dC,
                                     eprj, encH, lens, Wc16, bcomb, A16, syncv, t);
  vocab_mfma<<<dim3(VTn/128, Rn/128), 256, 0, stream>>>(A16, W16, bvoc, stats);
  tail<<<Rn/4, 256, 0, stream>>>(stats, A16, Wvoc, bvoc, gtgt, (float*)d_out);
}

// Round 7
// 2281.592 us; speedup vs baseline: 1.9339x; 1.9339x over previous
//
#include <hip/hip_runtime.h>
#include <math.h>

#define En 256
#define Hn 512
#define Bn 64
#define Sn 40
#define Tn 40
#define VTn 32000
#define Rn (Tn*Bn)
#define NCH 500   // 32000/64 stat chunks

typedef short v8s __attribute__((ext_vector_type(8)));
typedef float v4f __attribute__((ext_vector_type(4)));
typedef _Float16 h2v __attribute__((ext_vector_type(2)));

#if defined(__has_builtin)
#  if __has_builtin(__builtin_amdgcn_fdot2)
#    define HAVE_FDOT2 1
#  endif
#endif

__device__ __forceinline__ float dot4(float4 a, float4 b){
  return a.x*b.x + a.y*b.y + a.z*b.z + a.w*b.w;
}
__device__ __forceinline__ float sigm(float x){ return 1.f/(1.f+__expf(-x)); }
__device__ __forceinline__ unsigned short f2bf(float f){
  unsigned u = __float_as_uint(f);
  unsigned r = u + 0x7FFFu + ((u>>16)&1u);
  return (unsigned short)(r>>16);
}
__device__ __forceinline__ float bf2f(unsigned short u){
  return __uint_as_float(((unsigned)u)<<16);
}
__device__ __forceinline__ unsigned pkbf(float a, float b){
  return (unsigned)f2bf(a) | ((unsigned)f2bf(b)<<16);
}
__device__ __forceinline__ unsigned pkh(float a, float b){
  _Float16 ha = (_Float16)a, hb = (_Float16)b;
  unsigned short ua = __builtin_bit_cast(unsigned short, ha);
  unsigned short ub = __builtin_bit_cast(unsigned short, hb);
  return (unsigned)ua | ((unsigned)ub<<16);
}
__device__ __forceinline__ float fd2(unsigned w, unsigned h, float c){
#ifdef HAVE_FDOT2
  return __builtin_amdgcn_fdot2(__builtin_bit_cast(h2v,w), __builtin_bit_cast(h2v,h), c, false);
#else
  h2v a = __builtin_bit_cast(h2v,w), b = __builtin_bit_cast(h2v,h);
  return c + (float)a[0]*(float)b[0] + (float)a[1]*(float)b[1];
#endif
}

// ============ prep: zero states + maps + weight converts (1 launch) ============
// ranges: 209 zero | 10 maps | 512 Whf | 512 Whb | 1024 Wd | 384 Wcomb(f16)
__global__ void prep(float* zero_base,
                     const int* __restrict__ src, const int* __restrict__ tgt,
                     const int* __restrict__ lens, int* __restrict__ grev,
                     int* __restrict__ gtgt,
                     const float* __restrict__ Whh_f, unsigned short* __restrict__ Whf16,
                     const float* __restrict__ Whh_b, unsigned short* __restrict__ Whb16,
                     const float* __restrict__ Whh_d, const float* __restrict__ Wih_d,
                     unsigned short* __restrict__ Wd16,
                     const float* __restrict__ Wcomb, unsigned short* __restrict__ Wc16){
  int blk = blockIdx.x, tid = threadIdx.x;
  if (blk < 209){
    ((float4*)zero_base)[blk*256 + tid] = make_float4(0.f,0.f,0.f,0.f);
    return;
  }
  blk -= 209;
  if (blk < 10){
    int r = blk*256 + tid;
    if (r < Bn*Sn){
      int b = r/Sn, s = r%Sn;
      int j = lens[b]-1-s;
      grev[r] = (j>=0) ? src[b*Sn+j] : -1;
      int t2 = r>>6, b2 = r&63;
      gtgt[r] = tgt[b2*Tn + t2];
    }
    return;
  }
  blk -= 10;
  if (blk < 512){
    size_t e = ((size_t)blk*256 + tid)*8;
    float4 a = *(const float4*)(Whh_f+e), b = *(const float4*)(Whh_f+e+4);
    uint4 u; u.x=pkbf(a.x,a.y); u.y=pkbf(a.z,a.w); u.z=pkbf(b.x,b.y); u.w=pkbf(b.z,b.w);
    *(uint4*)(Whf16+e) = u;
    return;
  }
  blk -= 512;
  if (blk < 512){
    size_t e = ((size_t)blk*256 + tid)*8;
    float4 a = *(const float4*)(Whh_b+e), b = *(const float4*)(Whh_b+e+4);
    uint4 u; u.x=pkbf(a.x,a.y); u.y=pkbf(a.z,a.w); u.z=pkbf(b.x,b.y); u.w=pkbf(b.z,b.w);
    *(uint4*)(Whb16+e) = u;
    return;
  }
  blk -= 512;
  if (blk < 1024){
    size_t e = ((size_t)blk*256 + tid)*8;     // [2048][1024]: k<512 Whh_d, else Wih_d cols 256+
    int row = (int)(e>>10), k = (int)(e&1023);
    const float* sp = (k<512) ? (Whh_d + (size_t)row*512 + k)
                              : (Wih_d + (size_t)row*768 + 256 + (k-512));
    float4 a = *(const float4*)sp, b = *(const float4*)(sp+4);
    uint4 u; u.x=pkbf(a.x,a.y); u.y=pkbf(a.z,a.w); u.z=pkbf(b.x,b.y); u.w=pkbf(b.z,b.w);
    *(uint4*)(Wd16+e) = u;
    return;
  }
  blk -= 1024;
  { // Wcomb -> f16, 384 blocks
    size_t e = ((size_t)blk*256 + tid)*8;
    float4 a = *(const float4*)(Wcomb+e), b = *(const float4*)(Wcomb+e+4);
    uint4 u; u.x=pkh(a.x,a.y); u.y=pkh(a.z,a.w); u.z=pkh(b.x,b.y); u.w=pkh(b.z,b.w);
    *(uint4*)(Wc16+e) = u;
  }
}

// ============ generic bf16-staging MFMA GEMM: C[M,N] = gather(A)f32 @ Bf32^T + bias ============
struct GArg {
  const float* A; const int* gth; int lda;
  const float* B; int ldb;
  const float* bias; float* C; int ldc; int K;
};
struct GArg3 { GArg a[3]; };

__global__ __launch_bounds__(256) void ggemm(GArg3 p3){
  GArg d = p3.a[blockIdx.z];
  __shared__ unsigned short Abf[128*64];
  __shared__ unsigned short Bbf[128*64];
  const int n0 = blockIdx.x*128, r0 = blockIdx.y*128;
  const int tid = threadIdx.x;
  const int w = tid>>6, lane = tid&63;
  const int wr = w>>1, wc = w&1;
  v4f acc[4][4];
#pragma unroll
  for (int i=0;i<4;++i)
#pragma unroll
    for (int j=0;j<4;++j) acc[i][j] = (v4f){0.f,0.f,0.f,0.f};
  const int srow = tid>>1, kc = (tid&1)*32;
  int ar = d.gth ? d.gth[r0+srow] : (r0+srow);
  const float* Arow = (ar>=0) ? (d.A + (size_t)ar*d.lda) : nullptr;
  const float* Brow = d.B + (size_t)(n0+srow)*d.ldb;
  for (int kb=0; kb<d.K; kb+=64){
    __syncthreads();
#pragma unroll
    for (int c=0;c<4;++c){
      int k = kc + c*8;
      int swz = k ^ ((srow&7)<<3);
      uint4 ua;
      if (Arow){
        float4 x0 = *(const float4*)(Arow+kb+k);
        float4 x1 = *(const float4*)(Arow+kb+k+4);
        ua.x=pkbf(x0.x,x0.y); ua.y=pkbf(x0.z,x0.w); ua.z=pkbf(x1.x,x1.y); ua.w=pkbf(x1.z,x1.w);
      } else ua = make_uint4(0,0,0,0);
      *(uint4*)&Abf[srow*64 + swz] = ua;
      float4 y0 = *(const float4*)(Brow+kb+k);
      float4 y1 = *(const float4*)(Brow+kb+k+4);
      uint4 ub; ub.x=pkbf(y0.x,y0.y); ub.y=pkbf(y0.z,y0.w); ub.z=pkbf(y1.x,y1.y); ub.w=pkbf(y1.z,y1.w);
      *(uint4*)&Bbf[srow*64 + swz] = ub;
    }
    __syncthreads();
#pragma unroll
    for (int kk=0; kk<64; kk+=32){
      int kfr = kk + (lane>>4)*8;
      v8s bfr[4];
#pragma unroll
      for (int ni=0;ni<4;++ni){
        int brow = wc*64 + ni*16 + (lane&15);
        bfr[ni] = *(const v8s*)&Bbf[brow*64 + (kfr ^ ((brow&7)<<3))];
      }
#pragma unroll
      for (int mi=0;mi<4;++mi){
        int arl = wr*64 + mi*16 + (lane&15);
        v8s af = *(const v8s*)&Abf[arl*64 + (kfr ^ ((arl&7)<<3))];
#pragma unroll
        for (int ni=0;ni<4;++ni)
          acc[mi][ni] = __builtin_amdgcn_mfma_f32_16x16x32_bf16(af, bfr[ni], acc[mi][ni], 0,0,0);
      }
    }
  }
#pragma unroll
  for (int ni=0;ni<4;++ni){
    int col = n0 + wc*64 + ni*16 + (lane&15);
    float bb = d.bias[col];
#pragma unroll
    for (int mi=0;mi<4;++mi)
#pragma unroll
      for (int r=0;r<4;++r){
        int row = r0 + wr*64 + mi*16 + (lane>>4)*4 + r;
        d.C[(size_t)row*d.ldc + col] = acc[mi][ni][r] + bb;
      }
  }
}

// ============ encoder step: full-K MFMA gates + LSTM, both dirs (1 launch/step) ============
// blocks 0..63: dir = bx>>5, u-tile = bx&31 (16 u each).
// blocks 64..263: Wvoc->bf16 conversion slice (1/40th per step, idle-CU work).
__global__ __launch_bounds__(256) void enc_step(
    const unsigned short* __restrict__ hf_in, unsigned short* __restrict__ hf_out,
    const unsigned short* __restrict__ hb_in, unsigned short* __restrict__ hb_out,
    float* __restrict__ cF, float* __restrict__ cB,
    const unsigned short* __restrict__ Wf16, const unsigned short* __restrict__ Wb16,
    const float* __restrict__ Gf, const float* __restrict__ Gb,
    float* __restrict__ encH, float* __restrict__ outR,
    const int* __restrict__ lens,
    const float* __restrict__ Wvoc, unsigned short* __restrict__ W16, int s){
  const int bxall = blockIdx.x;
  const int tid = threadIdx.x;
  if (bxall >= 64){
    int chunk = s*200 + (bxall - 64);
    if (chunk < 8000){
      size_t e = ((size_t)chunk*256 + tid)*8;
      float4 a = *(const float4*)(Wvoc+e), b = *(const float4*)(Wvoc+e+4);
      uint4 u; u.x=pkbf(a.x,a.y); u.y=pkbf(a.z,a.w); u.z=pkbf(b.x,b.y); u.w=pkbf(b.z,b.w);
      *(uint4*)(W16+e) = u;
    }
    return;
  }
  __shared__ unsigned short Wls[64*64];
  __shared__ unsigned short Hls[64*64];
  __shared__ float Cls[64][66];
  const int bx = bxall;
  const int dir = bx>>5;
  const int u0 = (bx&31)*16;
  const unsigned short* Wm16 = dir ? Wb16 : Wf16;
  const unsigned short* hin = dir ? hb_in : hf_in;
  unsigned short* hout      = dir ? hb_out : hf_out;
  float* c = dir ? cB : cF;
  const float* G = dir ? Gb : Gf;
  const int w = tid>>6, lane = tid&63;
  v4f acc[4];
#pragma unroll
  for (int ni=0;ni<4;++ni) acc[ni] = (v4f){0.f,0.f,0.f,0.f};
  const int l = tid>>2;
  const int kc4 = (tid&3)*16;
  const int grow = (l>>4)*512 + u0 + (l&15);
  const unsigned short* Wrow = Wm16 + (size_t)grow*512;
  const unsigned short* Hrow = hin + (size_t)l*512;
  for (int kb=0; kb<512; kb+=64){
    __syncthreads();
#pragma unroll
    for (int c2=0;c2<2;++c2){
      int k = kc4 + c2*8;
      int swz = k ^ ((l&7)<<3);
      *(uint4*)&Wls[l*64+swz] = *(const uint4*)(Wrow + kb + k);
      *(uint4*)&Hls[l*64+swz] = *(const uint4*)(Hrow + kb + k);
    }
    __syncthreads();
#pragma unroll
    for (int kk=0; kk<64; kk+=32){
      int kfr = kk + (lane>>4)*8;
      int mrow = w*16 + (lane&15);
      v8s af = *(const v8s*)&Wls[mrow*64 + (kfr ^ ((mrow&7)<<3))];
#pragma unroll
      for (int ni=0;ni<4;++ni){
        int brow = ni*16 + (lane&15);
        v8s bf = *(const v8s*)&Hls[brow*64 + (kfr ^ ((brow&7)<<3))];
        acc[ni] = __builtin_amdgcn_mfma_f32_16x16x32_bf16(af, bf, acc[ni], 0,0,0);
      }
    }
  }
#pragma unroll
  for (int ni=0;ni<4;++ni)
#pragma unroll
    for (int r=0;r<4;++r)
      Cls[w*16 + (lane>>4)*4 + r][ni*16 + (lane&15)] = acc[ni][r];
  __syncthreads();
  const int u_l = tid&15, bq = tid>>4;
#pragma unroll
  for (int j=0;j<4;++j){
    int b = bq + j*16;
    size_t gidx = ((size_t)(b*Sn+s))*2048 + u0 + u_l;
    float gi = Cls[u_l][b]      + G[gidx];
    float gf = Cls[16+u_l][b]   + G[gidx+512];
    float gg = Cls[32+u_l][b]   + G[gidx+1024];
    float go = Cls[48+u_l][b]   + G[gidx+1536];
    int bu = b*512 + u0 + u_l;
    bool valid = s < lens[b];
    float cp = c[bu];
    float cn = sigm(gf)*cp + sigm(gi)*tanhf(gg);
    float hn = sigm(go)*tanhf(cn);
    c[bu] = valid ? cn : cp;
    hout[bu] = valid ? f2bf(hn) : hin[bu];
    if (dir==0) encH[((size_t)(b*Sn+s))*1024 + u0+u_l] = valid ? hn : 0.f;
    else        outR[((size_t)(b*Sn+s))*512  + u0+u_l] = valid ? hn : 0.f;
  }
}

// ============ mid: proj-h/proj-c + reverse-bwd (1 launch, 768 blocks) ============
__global__ void mid_fused(const unsigned short* __restrict__ h16f,
                          const unsigned short* __restrict__ h16b,
                          const float* __restrict__ cF, const float* __restrict__ cB,
                          const float* __restrict__ Whp, const float* __restrict__ bhp,
                          const float* __restrict__ Wcp, const float* __restrict__ bcp,
                          unsigned short* __restrict__ ho0, float* __restrict__ dC,
                          const float* __restrict__ outR, const int* __restrict__ lens,
                          float* __restrict__ encH){
  int blk = blockIdx.x, tid = threadIdx.x;
  if (blk < 128){
    int isC = blk >= 64;
    int idx = (blk & 63)*256 + tid;
#pragma unroll
    for (int e=0;e<2;++e){
      int o = idx*2 + e;
      int b = o>>9, u = o&511;
      if (!isC){
        const float* wr = Whp + (size_t)u*1024;
        float acc = bhp[u];
        const uint4* hf4 = (const uint4*)(h16f + (size_t)b*512);
        for (int q=0;q<64;++q){
          uint4 v = hf4[q];
          unsigned uu[4] = {v.x,v.y,v.z,v.w};
#pragma unroll
          for (int i2=0;i2<4;++i2){
            acc += bf2f((unsigned short)(uu[i2]&0xFFFF))*wr[q*8+i2*2];
            acc += bf2f((unsigned short)(uu[i2]>>16))   *wr[q*8+i2*2+1];
          }
        }
        const uint4* hb4 = (const uint4*)(h16b + (size_t)b*512);
        const float* wr2 = wr + 512;
        for (int q=0;q<64;++q){
          uint4 v = hb4[q];
          unsigned uu[4] = {v.x,v.y,v.z,v.w};
#pragma unroll
          for (int i2=0;i2<4;++i2){
            acc += bf2f((unsigned short)(uu[i2]&0xFFFF))*wr2[q*8+i2*2];
            acc += bf2f((unsigned short)(uu[i2]>>16))   *wr2[q*8+i2*2+1];
          }
        }
        ho0[b*1024 + u] = f2bf(acc);
      } else {
        const float4* w4 = (const float4*)(Wcp + (size_t)u*1024);
        float acc = bcp[u];
        const float4* x1 = (const float4*)(cF + (size_t)b*512);
        const float4* x2 = (const float4*)(cB + (size_t)b*512);
        for (int q=0;q<128;++q) acc += dot4(x1[q], w4[q]);
        for (int q=0;q<128;++q) acc += dot4(x2[q], w4[128+q]);
        dC[b*512 + u] = acc;
      }
    }
    return;
  }
  blk -= 128;
  { // reverse-bwd, 640 blocks
    int e = (blk*256 + tid)*8;       // < 1,310,720
    int u = e & 511;
    int bsi = e >> 9;
    int s = bsi % Sn, b = bsi / Sn;
    int len = lens[b];
    float4 v0 = make_float4(0,0,0,0), v1 = make_float4(0,0,0,0);
    if (s < len){
      int j = len-1-s;
      const float* sp = outR + ((size_t)(b*Sn+j))*512 + u;
      v0 = *(const float4*)sp; v1 = *(const float4*)(sp+4);
    }
    float* dp = encH + ((size_t)(b*Sn+s))*1024 + 512 + u;
    *(float4*)dp = v0; *(float4*)(dp+4) = v1;
  }
}

// ============ decoder K_A: MFMA gates (K=1024 over [h|o]) + LSTM ============
// grid 32: u-tile (16 u). writes h(t) bf16 into ho_next h-part.
__global__ __launch_bounds__(256) void dec_gates(
    const unsigned short* __restrict__ Wd16, const unsigned short* __restrict__ ho_cur,
    unsigned short* __restrict__ ho_next, const float* __restrict__ Gdy,
    float* __restrict__ dC, int t){
  __shared__ unsigned short Wls[64*64];
  __shared__ unsigned short Hls[64*64];
  __shared__ float Cls[64][66];
  const int u0 = blockIdx.x*16;
  const int tid = threadIdx.x, w = tid>>6, lane = tid&63;
  v4f acc[4];
#pragma unroll
  for (int ni=0;ni<4;++ni) acc[ni] = (v4f){0.f,0.f,0.f,0.f};
  const int l = tid>>2;
  const int kc4 = (tid&3)*16;
  const int grow = (l>>4)*512 + u0 + (l&15);
  const unsigned short* Wrow = Wd16 + (size_t)grow*1024;
  const unsigned short* Hrow = ho_cur + (size_t)l*1024;
  for (int kb=0; kb<1024; kb+=64){
    __syncthreads();
#pragma unroll
    for (int c2=0;c2<2;++c2){
      int k = kc4 + c2*8;
      int swz = k ^ ((l&7)<<3);
      *(uint4*)&Wls[l*64+swz] = *(const uint4*)(Wrow + kb + k);
      *(uint4*)&Hls[l*64+swz] = *(const uint4*)(Hrow + kb + k);
    }
    __syncthreads();
#pragma unroll
    for (int kk=0; kk<64; kk+=32){
      int kfr = kk + (lane>>4)*8;
      int mrow = w*16 + (lane&15);
      v8s af = *(const v8s*)&Wls[mrow*64 + (kfr ^ ((mrow&7)<<3))];
#pragma unroll
      for (int ni=0;ni<4;++ni){
        int brow = ni*16 + (lane&15);
        v8s bf = *(const v8s*)&Hls[brow*64 + (kfr ^ ((brow&7)<<3))];
        acc[ni] = __builtin_amdgcn_mfma_f32_16x16x32_bf16(af, bf, acc[ni], 0,0,0);
      }
    }
  }
#pragma unroll
  for (int ni=0;ni<4;++ni)
#pragma unroll
    for (int r=0;r<4;++r)
      Cls[w*16 + (lane>>4)*4 + r][ni*16 + (lane&15)] = acc[ni][r];
  __syncthreads();
  const int u_l = tid&15, bq = tid>>4;
#pragma unroll
  for (int j=0;j<4;++j){
    int b = bq + j*16;
    size_t gidx = ((size_t)(t*Bn+b))*2048 + u0 + u_l;
    float gi = Cls[u_l][b]      + Gdy[gidx];
    float gf = Cls[16+u_l][b]   + Gdy[gidx+512];
    float gg = Cls[32+u_l][b]   + Gdy[gidx+1024];
    float go = Cls[48+u_l][b]   + Gdy[gidx+1536];
    int bu = b*512 + u0 + u_l;
    float cp = dC[bu];
    float cn = sigm(gf)*cp + sigm(gi)*tanhf(gg);
    float hn = sigm(go)*tanhf(cn);
    dC[bu] = cn;
    ho_next[b*1024 + u0 + u_l] = f2bf(hn);
  }
}

// ============ decoder K_BC: attention + combine (4 blocks/batch) ============
// grid 256: b = bx>>2, q = bx&3 (combine rows q*128..+128). writes o bf16 + A16 row.
__global__ __launch_bounds__(256) void dec_attcomb(
    unsigned short* __restrict__ ho_next, const float* __restrict__ eprj,
    const float* __restrict__ encH, const int* __restrict__ lens,
    const unsigned short* __restrict__ Wc16, const float* __restrict__ bcomb,
    unsigned short* __restrict__ A16, int t){
  const int b = blockIdx.x >> 2;
  const int q = blockIdx.x & 3;
  const int tid = threadIdx.x;
  __shared__ __align__(16) float hs[512];
  __shared__ __align__(16) float als[1024];
  __shared__ float es[Sn], sal[Sn];
  __shared__ float sinv;
  __shared__ __align__(16) unsigned int ha16[768];
  __shared__ float ps[128][2];
  for (int i=tid; i<512; i+=256) hs[i] = bf2f(ho_next[b*1024 + i]);
  __syncthreads();
  const int wv = tid>>6, lane = tid&63;
  const int len = lens[b];
  for (int si=0; si<10; ++si){
    int s2 = wv*10 + si;
    const float* pr = eprj + ((size_t)(b*Sn+s2))*512 + lane*8;
    float4 p0 = *(const float4*)pr, p1 = *(const float4*)(pr+4);
    const float* hh = hs + lane*8;
    float4 h0 = *(const float4*)hh, h1 = *(const float4*)(hh+4);
    float a = dot4(p0,h0) + dot4(p1,h1);
#pragma unroll
    for (int off=32; off; off>>=1) a += __shfl_down(a, off);
    if (lane==0) es[s2] = (s2>=1 && s2<len) ? -INFINITY : a;
  }
  __syncthreads();
  if (tid < 64){
    float e2 = (tid<Sn) ? es[tid] : -INFINITY;
    float m = e2;
#pragma unroll
    for (int off=32; off; off>>=1) m = fmaxf(m, __shfl_xor(m, off));
    float p = (tid<Sn) ? __expf(e2-m) : 0.f;
    float sum = p;
#pragma unroll
    for (int off=32; off; off>>=1) sum += __shfl_xor(sum, off);
    if (tid<Sn) sal[tid] = p;
    if (tid==0) sinv = 1.f/sum;
  }
  __syncthreads();
  float inv = sinv;
#pragma unroll
  for (int dq=0; dq<4; ++dq){
    int d = dq*256 + tid;
    float acc = 0.f;
    for (int s2=0; s2<Sn; ++s2) acc += sal[s2]*encH[((size_t)(b*Sn+s2))*1024 + d];
    als[d] = acc*inv;
  }
  __syncthreads();
  for (int p=tid; p<768; p+=256){
    int i0 = 2*p, i1 = 2*p+1;
    float x0 = (i0<512) ? hs[i0] : als[i0-512];
    float x1 = (i1<512) ? hs[i1] : als[i1-512];
    ha16[p] = pkh(x0, x1);
  }
  __syncthreads();
  const int rloc = tid & 127;
  const int kh = tid >> 7;
  const int row = q*128 + rloc;
  const uint4* wp = (const uint4*)(Wc16 + (size_t)row*1536 + kh*768);
  const uint4* hp = (const uint4*)&ha16[kh*384];
  float a0 = 0.f;
#pragma unroll 4
  for (int qq=0; qq<96; ++qq){
    uint4 wv4 = wp[qq];
    uint4 hv4 = hp[qq];
    a0 = fd2(wv4.x, hv4.x, a0);
    a0 = fd2(wv4.y, hv4.y, a0);
    a0 = fd2(wv4.z, hv4.z, a0);
    a0 = fd2(wv4.w, hv4.w, a0);
  }
  ps[rloc][kh] = a0;
  __syncthreads();
  if (tid < 128){
    int r2 = q*128 + tid;
    float O = tanhf(ps[tid][0] + ps[tid][1] + bcomb[r2]);
    unsigned short ob = f2bf(O);
    ho_next[b*1024 + 512 + r2] = ob;
    A16[((size_t)(t*Bn+b))*512 + r2] = ob;
  }
}

// ============ vocab MFMA (round-4 proven): 128x128 tiles, fused per-64-col stats ============
__global__ __launch_bounds__(256) void vocab_mfma(
    const unsigned short* __restrict__ A16, const unsigned short* __restrict__ W16,
    const float* __restrict__ bv, float* __restrict__ stats){
  __shared__ unsigned short Abf[128*64];
  __shared__ unsigned short Bbf[128*64];
  const int vb = blockIdx.x, rb = blockIdx.y;
  const int r0 = rb*128, v0 = vb*128;
  const int tid = threadIdx.x;
  const int w = tid>>6, lane = tid&63;
  const int wr = w>>1, wc = w&1;
  v4f acc[4][4];
#pragma unroll
  for (int i=0;i<4;++i)
#pragma unroll
    for (int j=0;j<4;++j) acc[i][j] = (v4f){0.f,0.f,0.f,0.f};
  const int srow = tid>>1;
  const int sk0  = (tid&1)*8;
  const int arow = wr*64 + (lane&15);
  const int brow = wc*64 + (lane&15);
  const int kfrag = (lane>>4)*8;
  for (int ks=0; ks<8; ++ks){
    const int kb = ks*64;
    __syncthreads();
#pragma unroll
    for (int c=0;c<4;++c){
      int k = sk0 + c*16;
      int swz = k ^ ((srow&7)<<3);
      *(uint4*)&Abf[srow*64 + swz] = *(const uint4*)(A16 + (size_t)(r0+srow)*512 + kb + k);
      *(uint4*)&Bbf[srow*64 + swz] = *(const uint4*)(W16 + (size_t)(v0+srow)*512 + kb + k);
    }
    __syncthreads();
#pragma unroll
    for (int kk=0; kk<64; kk+=32){
      v8s af[4], bf[4];
#pragma unroll
      for (int mi=0;mi<4;++mi){
        int row = arow + mi*16;
        int k = kk + kfrag;
        af[mi] = *(const v8s*)&Abf[row*64 + (k ^ ((row&7)<<3))];
      }
#pragma unroll
      for (int ni=0;ni<4;++ni){
        int row = brow + ni*16;
        int k = kk + kfrag;
        bf[ni] = *(const v8s*)&Bbf[row*64 + (k ^ ((row&7)<<3))];
      }
#pragma unroll
      for (int mi=0;mi<4;++mi)
#pragma unroll
        for (int ni=0;ni<4;++ni)
          acc[mi][ni] = __builtin_amdgcn_mfma_f32_16x16x32_bf16(af[mi], bf[ni], acc[mi][ni], 0,0,0);
    }
  }
  float bj[4];
#pragma unroll
  for (int ni=0;ni<4;++ni) bj[ni] = bv[v0 + wc*64 + ni*16 + (lane&15)];
#pragma unroll
  for (int mi=0;mi<4;++mi){
#pragma unroll
    for (int r=0;r<4;++r){
      float x0 = acc[mi][0][r]+bj[0], x1 = acc[mi][1][r]+bj[1];
      float x2 = acc[mi][2][r]+bj[2], x3 = acc[mi][3][r]+bj[3];
      float mx = fmaxf(fmaxf(x0,x1), fmaxf(x2,x3));
#pragma unroll
      for (int off=1; off<16; off<<=1) mx = fmaxf(mx, __shfl_xor(mx, off));
      float se = __expf(x0-mx)+__expf(x1-mx)+__expf(x2-mx)+__expf(x3-mx);
#pragma unroll
      for (int off=1; off<16; off<<=1) se += __shfl_xor(se, off);
      if ((lane&15)==0){
        int row = r0 + wr*64 + mi*16 + (lane>>4)*4 + r;
        int chunk = vb*2 + wc;
        size_t o = ((size_t)row*NCH + chunk)*2;
        stats[o]   = mx;
        stats[o+1] = se;
      }
    }
  }
}

// ============ tail: lse + target logit + atomic mean (1 launch) ============
__global__ void tail(const float* __restrict__ stats, const unsigned short* __restrict__ A16,
                     const float* __restrict__ Wvoc, const float* __restrict__ bvoc,
                     const int* __restrict__ gtgt, float* __restrict__ out){
  int r = blockIdx.x*4 + (threadIdx.x>>6);
  int lane = threadIdx.x & 63;
  const float* st = stats + (size_t)r*NCH*2;
  float M = -INFINITY;
  for (int c=lane; c<NCH; c+=64) M = fmaxf(M, st[2*c]);
#pragma unroll
  for (int off=32; off; off>>=1) M = fmaxf(M, __shfl_xor(M, off));
  float S = 0.f;
  for (int c=lane; c<NCH; c+=64) S += __expf(st[2*c]-M)*st[2*c+1];
#pragma unroll
  for (int off=32; off; off>>=1) S += __shfl_xor(S, off);
  int v = gtgt[r];
  int k = lane*8;
  uint4 a4 = *(const uint4*)(A16 + (size_t)r*512 + k);
  const float* wvp = Wvoc + (size_t)v*512 + k;
  float4 w0 = *(const float4*)wvp, w1 = *(const float4*)(wvp+4);
  unsigned uu[4] = {a4.x, a4.y, a4.z, a4.w};
  float dot = 0.f;
  dot += bf2f((unsigned short)(uu[0]&0xFFFF))*w0.x + bf2f((unsigned short)(uu[0]>>16))*w0.y;
  dot += bf2f((unsigned short)(uu[1]&0xFFFF))*w0.z + bf2f((unsigned short)(uu[1]>>16))*w0.w;
  dot += bf2f((unsigned short)(uu[2]&0xFFFF))*w1.x + bf2f((unsigned short)(uu[2]>>16))*w1.y;
  dot += bf2f((unsigned short)(uu[3]&0xFFFF))*w1.z + bf2f((unsigned short)(uu[3]>>16))*w1.w;
#pragma unroll
  for (int off=32; off; off>>=1) dot += __shfl_down(dot, off);
  if (lane==0){
    float lse = M + logf(S);
    float nll = lse - (dot + bvoc[v]);
    atomicAdd(out, nll * (1.0f/(float)Rn));
  }
}

extern "C" void kernel_launch(void* const* d_in, const int* in_sizes, int n_in,
                              void* d_out, int out_size, void* d_ws, size_t ws_size,
                              hipStream_t stream){
  (void)in_sizes; (void)n_in; (void)out_size; (void)ws_size;
  const int*   srcP  = (const int*)  d_in[0];
  const int*   tgtP  = (const int*)  d_in[1];
  const int*   lens  = (const int*)  d_in[2];
  const float* semb  = (const float*)d_in[3];
  const float* temb  = (const float*)d_in[4];
  const float* Wih_f = (const float*)d_in[5];
  const float* Whh_f = (const float*)d_in[6];
  const float* b_f   = (const float*)d_in[7];
  const float* Wih_b = (const float*)d_in[8];
  const float* Whh_b = (const float*)d_in[9];
  const float* b_b   = (const float*)d_in[10];
  const float* Wih_d = (const float*)d_in[11];
  const float* Whh_d = (const float*)d_in[12];
  const float* b_d   = (const float*)d_in[13];
  const float* Whp   = (const float*)d_in[14];
  const float* bhp   = (const float*)d_in[15];
  const float* Wcp   = (const float*)d_in[16];
  const float* bcp   = (const float*)d_in[17];
  const float* Watt  = (const float*)d_in[18];
  const float* batt  = (const float*)d_in[19];
  const float* Wcomb = (const float*)d_in[20];
  const float* bcomb = (const float*)d_in[21];
  const float* Wvoc  = (const float*)d_in[22];
  const float* bvoc  = (const float*)d_in[23];

  float* w = (float*)d_ws;
  size_t off = 0;
  auto alloc = [&](size_t n){ float* p = w + off; off += n; return p; };
  float* encH = alloc(2621440);          // [2560][1024]; stats alias after decoder
  float* outR = alloc(1310720);
  float* eprj = alloc(1310720);
  float* Gf   = alloc(5242880);
  float* Gb   = alloc(5242880);
  float* Gdy  = alloc(5242880);
  unsigned short* W16   = (unsigned short*)alloc((size_t)VTn*Hn/2);   // 8.19M floats
  unsigned short* A16   = (unsigned short*)alloc(655360);
  unsigned short* Whf16 = (unsigned short*)alloc(524288);
  unsigned short* Whb16 = (unsigned short*)alloc(524288);
  unsigned short* Wd16  = (unsigned short*)alloc(1048576);
  unsigned short* Wc16  = (unsigned short*)alloc(393216);
  float* zero_base = w + off;            // zeroed by prep (209 blocks x 1024 floats)
  float* cF = alloc(32768);
  float* cB = alloc(32768);
  float* dC = alloc(32768);
  unsigned short* h16f0 = (unsigned short*)alloc(16384);
  unsigned short* h16f1 = (unsigned short*)alloc(16384);
  unsigned short* h16b0 = (unsigned short*)alloc(16384);
  unsigned short* h16b1 = (unsigned short*)alloc(16384);
  unsigned short* ho0   = (unsigned short*)alloc(32768);
  unsigned short* ho1   = (unsigned short*)alloc(32768);
  int* grev = (int*)alloc(2560);
  int* gtgt = (int*)alloc(2560);
  float* stats = encH;                   // over encH (dead post-decoder)

  hipMemsetAsync(d_out, 0, sizeof(float), stream);
  prep<<<2651, 256, 0, stream>>>(zero_base, srcP, tgtP, lens, grev, gtgt,
                                 Whh_f, Whf16, Whh_b, Whb16, Whh_d, Wih_d, Wd16,
                                 Wcomb, Wc16);
  {
    GArg3 g;
    g.a[0] = GArg{semb, srcP, En, Wih_f, En,  b_f, Gf,  2048, En};
    g.a[1] = GArg{semb, grev, En, Wih_b, En,  b_b, Gb,  2048, En};
    g.a[2] = GArg{temb, gtgt, En, Wih_d, 768, b_d, Gdy, 2048, En};
    ggemm<<<dim3(16,20,3), 256, 0, stream>>>(g);
  }
  // encoder: 40 launches; each also converts 1/40 of Wvoc on idle CUs
  for (int s=0; s<Sn; ++s){
    const unsigned short* hfi = (s&1) ? h16f1 : h16f0;
    unsigned short*       hfo = (s&1) ? h16f0 : h16f1;
    const unsigned short* hbi = (s&1) ? h16b1 : h16b0;
    unsigned short*       hbo = (s&1) ? h16b0 : h16b1;
    enc_step<<<264, 256, 0, stream>>>(hfi, hfo, hbi, hbo, cF, cB,
                                      Whf16, Whb16, Gf, Gb, encH, outR, lens,
                                      Wvoc, W16, s);
  }
  mid_fused<<<768, 256, 0, stream>>>(h16f0, h16b0, cF, cB, Whp, bhp, Wcp, bcp,
                                     ho0, dC, outR, lens, encH);
  {
    GArg3 g;
    g.a[0] = GArg{encH, nullptr, 1024, Watt, 1024, batt, eprj, 512, 1024};
    g.a[1] = g.a[0]; g.a[2] = g.a[0];
    ggemm<<<dim3(4,20,1), 256, 0, stream>>>(g);
  }
  unsigned short* Hb[2] = {ho0, ho1};
  for (int t=0; t<Tn; ++t){
    dec_gates<<<32, 256, 0, stream>>>(Wd16, Hb[t&1], Hb[(t+1)&1], Gdy, dC, t);
    dec_attcomb<<<256, 256, 0, stream>>>(Hb[(t+1)&1], eprj, encH, lens, Wc16, bcomb, A16, t);
  }
  vocab_mfma<<<dim3(VTn/128, Rn/128), 256, 0, stream>>>(A16, W16, bvoc, stats);
  tail<<<Rn/4, 256, 0, stream>>>(stats, A16, Wvoc, bvoc, gtgt, (float*)d_out);
}